// Round 7
// baseline (471.586 us; speedup 1.0000x reference)
//
#include <hip/hip_runtime.h>

typedef __bf16 bf16;
typedef __attribute__((ext_vector_type(4))) __bf16 bf16x4;
typedef __attribute__((ext_vector_type(8))) __bf16 bf16x8;
typedef __attribute__((ext_vector_type(4))) float f32x4;

__device__ __forceinline__ void stage16(const bf16* g, bf16* l) {
  __builtin_amdgcn_global_load_lds(
      (const __attribute__((address_space(1))) void*)g,
      (__attribute__((address_space(3))) void*)l, 16, 0, 0);
}

// ============= convert+transpose (fp32 [R][C] -> bf16 [C][R]) =============
__global__ __launch_bounds__(256)
void transpose_f32_bf16(const float* __restrict__ src, bf16* __restrict__ dst, int R, int C)
{
  __shared__ bf16 tile[32][33];
  const int tx = threadIdx.x & 31, ty = threadIdx.x >> 5;
  const int c0 = blockIdx.x * 32, r0 = blockIdx.y * 32;
#pragma unroll
  for (int i = 0; i < 4; ++i)
    tile[ty + i * 8][tx] = (bf16)src[(size_t)(r0 + ty + i * 8) * C + c0 + tx];
  __syncthreads();
#pragma unroll
  for (int i = 0; i < 4; ++i)
    dst[(size_t)(c0 + ty + i * 8) * R + r0 + tx] = tile[tx][ty + i * 8];
}

// ============= layernorm: fp32 in -> bf16 out (one wave per 1024-col row) =============
__global__ __launch_bounds__(256)
void ln_f32_bf16(const float* __restrict__ x, const float* __restrict__ g,
                 const float* __restrict__ bta, bf16* __restrict__ out)
{
  const int row = blockIdx.x * 4 + (threadIdx.x >> 6);
  const int l = threadIdx.x & 63;
  const float* xr = x + (size_t)row * 1024 + l * 16;
  f32x4 a[4];
#pragma unroll
  for (int i = 0; i < 4; ++i) a[i] = ((const f32x4*)xr)[i];
  float s = 0.f, s2 = 0.f;
#pragma unroll
  for (int i = 0; i < 4; ++i)
#pragma unroll
    for (int jj = 0; jj < 4; ++jj) { float vv = a[i][jj]; s += vv; s2 += vv * vv; }
#pragma unroll
  for (int m = 1; m < 64; m <<= 1) { s += __shfl_xor(s, m); s2 += __shfl_xor(s2, m); }
  const float mu = s * (1.0f / 1024.0f);
  const float var = s2 * (1.0f / 1024.0f) - mu * mu;
  const float rs = rsqrtf(var + 1e-5f);
  f32x4 gv[4], bv[4];
#pragma unroll
  for (int i = 0; i < 4; ++i) {
    gv[i] = ((const f32x4*)(g + l * 16))[i];
    bv[i] = ((const f32x4*)(bta + l * 16))[i];
  }
  bf16x8 o0, o1;
#pragma unroll
  for (int i = 0; i < 8; ++i) {
    float v0 = a[i >> 2][i & 3];
    float v1 = a[2 + (i >> 2)][i & 3];
    o0[i] = (bf16)((v0 - mu) * rs * gv[i >> 2][i & 3] + bv[i >> 2][i & 3]);
    o1[i] = (bf16)((v1 - mu) * rs * gv[2 + (i >> 2)][i & 3] + bv[2 + (i >> 2)][i & 3]);
  }
  bf16* orow = out + (size_t)row * 1024 + l * 16;
  ((bf16x8*)orow)[0] = o0;
  ((bf16x8*)orow)[1] = o1;
}

// ======== GEMM 256x256, BK=64, 8 waves, 8-phase-style schedule ========
// C[M,N] = A[M,K] @ Bt[N,K]^T.  LDS: [dbuf][half][128][64] per operand, read
// swizzle slot^=(row&7), inverse applied to global source (global_load_lds).
// EPI: 0 = fused QKV (seg0 q*0.125 [B,H,T,hd]; seg1 k [B,H,T,hd]; seg2 v [B,H,hd,T])
//      3 = fp32 out = acc + bias + fp32 residual (proj);
//      4 = bf16 out = gelu(acc + bias);
//      5 = fp32 out = acc + bias + fp32 residual (final).
template <int EPI>
__global__ __launch_bounds__(512, 2)
void gemm_bt(const bf16* __restrict__ A, const bf16* __restrict__ Bt,
             const float* __restrict__ bias, const float* __restrict__ biasK,
             const float* __restrict__ biasV,
             void* __restrict__ out, void* __restrict__ outK, void* __restrict__ outV,
             const float* __restrict__ res, int M, int N, int K)
{
  __shared__ bf16 As[2][2][128][64];   // 64 KB
  __shared__ bf16 Bs[2][2][128][64];   // 64 KB
  const int tid = threadIdx.x;
  const int l = tid & 63;
  const int w = tid >> 6;        // 0..7
  const int wm = w >> 2;         // 0..1  (row half)
  const int wn = w & 3;          // 0..3  (col quarter)
  const int m0 = blockIdx.x * 256;
  const int n0 = blockIdx.y * 256;

  // staging geometry: thread t -> row t>>3 (0..63), slot t&7; global col pre-swizzled
  const int srow = tid >> 3;
  const int sslot = tid & 7;
  const int gcolsw = ((sslot ^ (srow & 7)) << 3);   // elements
  const bf16* gA = A + (size_t)(m0 + srow) * K + gcolsw;
  const bf16* gB = Bt + (size_t)(n0 + srow) * K + gcolsw;

  const int lrow = l & 15;
  const int lgrp = l >> 4;       // 0..3

  f32x4 acc[8][4] = {};          // [mi][ni], mi over 128 rows, ni over 64 cols
  const int KT = K >> 6;

#define STA(buf, h, kb)                                                          \
  do {                                                                           \
    stage16(gA + (size_t)(h) * 128 * K + (kb), &As[buf][h][srow][sslot * 8]);    \
    stage16(gA + (size_t)((h) * 128 + 64) * K + (kb), &As[buf][h][64 + srow][sslot * 8]); \
  } while (0)
#define STB(buf, h, kb)                                                          \
  do {                                                                           \
    stage16(gB + (size_t)(h) * 128 * K + (kb), &Bs[buf][h][srow][sslot * 8]);    \
    stage16(gB + (size_t)((h) * 128 + 64) * K + (kb), &Bs[buf][h][64 + srow][sslot * 8]); \
  } while (0)
#define RDA(dst, mi, ks)                                                         \
  do {                                                                           \
    const int row_ = (mi) * 16 + lrow;                                           \
    const int sl_ = ((((ks) * 4 + lgrp) ^ (row_ & 7)) << 3);                     \
    dst = *(const bf16x8*)&As[cur][wm][row_][sl_];                               \
  } while (0)
#define RDB(dst, ni, ks)                                                         \
  do {                                                                           \
    const int row_ = (wn & 1) * 64 + (ni) * 16 + lrow;                           \
    const int sl_ = ((((ks) * 4 + lgrp) ^ (row_ & 7)) << 3);                     \
    dst = *(const bf16x8*)&Bs[cur][wn >> 1][row_][sl_];                          \
  } while (0)

  // prologue: stage K-tile 0 (8 loads in flight)
  STA(0, 0, 0); STA(0, 1, 0); STB(0, 0, 0); STB(0, 1, 0);

  for (int kt = 0; kt < KT; ++kt) {
    const int cur = kt & 1;
    const int nxt = cur ^ 1;
    const int kb = (kt + 1) << 6;
    const bool pf = (kt + 1 < KT);

    __builtin_amdgcn_s_barrier();                      // B1: buf nxt free to write
    if (pf) STA(nxt, 0, kb);
    if (pf) asm volatile("s_waitcnt vmcnt(2)" ::: "memory");
    else    asm volatile("s_waitcnt vmcnt(0)" ::: "memory");
    __builtin_amdgcn_sched_barrier(0);
    __builtin_amdgcn_s_barrier();                      // B2: buf cur ready for all

    bf16x8 a[4][2], b[4][2];
    // ---- phase 0: read A(mh0) + all B; MFMA quad (mh0, nh0..1)
#pragma unroll
    for (int mi = 0; mi < 4; ++mi) { RDA(a[mi][0], mi, 0); RDA(a[mi][1], mi, 1); }
#pragma unroll
    for (int ni = 0; ni < 4; ++ni) { RDB(b[ni][0], ni, 0); RDB(b[ni][1], ni, 1); }
    __builtin_amdgcn_s_setprio(1);
#pragma unroll
    for (int mi = 0; mi < 4; ++mi)
#pragma unroll
      for (int ni = 0; ni < 2; ++ni)
#pragma unroll
        for (int ks = 0; ks < 2; ++ks)
          acc[mi][ni] = __builtin_amdgcn_mfma_f32_16x16x32_bf16(a[mi][ks], b[ni][ks], acc[mi][ni], 0, 0, 0);
    __builtin_amdgcn_s_setprio(0);
    __builtin_amdgcn_s_barrier();
    // ---- phase 1: stage Ah1; MFMA quad (mh0, nh2..3)
    if (pf) STA(nxt, 1, kb);
    __builtin_amdgcn_s_setprio(1);
#pragma unroll
    for (int mi = 0; mi < 4; ++mi)
#pragma unroll
      for (int ni = 2; ni < 4; ++ni)
#pragma unroll
        for (int ks = 0; ks < 2; ++ks)
          acc[mi][ni] = __builtin_amdgcn_mfma_f32_16x16x32_bf16(a[mi][ks], b[ni][ks], acc[mi][ni], 0, 0, 0);
    __builtin_amdgcn_s_setprio(0);
    __builtin_amdgcn_s_barrier();
    // ---- phase 2: read A(mh1); stage Bh0; MFMA quad (mh1, nh0..1)
#pragma unroll
    for (int mi = 0; mi < 4; ++mi) { RDA(a[mi][0], 4 + mi, 0); RDA(a[mi][1], 4 + mi, 1); }
    if (pf) STB(nxt, 0, kb);
    __builtin_amdgcn_s_setprio(1);
#pragma unroll
    for (int mi = 0; mi < 4; ++mi)
#pragma unroll
      for (int ni = 0; ni < 2; ++ni)
#pragma unroll
        for (int ks = 0; ks < 2; ++ks)
          acc[4 + mi][ni] = __builtin_amdgcn_mfma_f32_16x16x32_bf16(a[mi][ks], b[ni][ks], acc[4 + mi][ni], 0, 0, 0);
    __builtin_amdgcn_s_setprio(0);
    __builtin_amdgcn_s_barrier();
    // ---- phase 3: stage Bh1; MFMA quad (mh1, nh2..3)
    if (pf) STB(nxt, 1, kb);
    __builtin_amdgcn_s_setprio(1);
#pragma unroll
    for (int mi = 0; mi < 4; ++mi)
#pragma unroll
      for (int ni = 2; ni < 4; ++ni)
#pragma unroll
        for (int ks = 0; ks < 2; ++ks)
          acc[4 + mi][ni] = __builtin_amdgcn_mfma_f32_16x16x32_bf16(a[mi][ks], b[ni][ks], acc[4 + mi][ni], 0, 0, 0);
    __builtin_amdgcn_s_setprio(0);
    __builtin_amdgcn_s_barrier();
  }
#undef STA
#undef STB
#undef RDA
#undef RDB

  // epilogue: C/D layout col = lane&15, row = (lane>>4)*4 + j
  const int seg = n0 >> 10;   // block-uniform (EPI 0; 256-tile never crosses seg)
  const float* bp = (EPI == 0) ? (seg == 0 ? bias : (seg == 1 ? biasK : biasV)) : bias;
#pragma unroll
  for (int mi = 0; mi < 8; ++mi) {
#pragma unroll
    for (int ni = 0; ni < 4; ++ni) {
      const int colg = n0 + wn * 64 + ni * 16 + lrow;
      const int col = (EPI == 0) ? (colg & 1023) : colg;
      const float bv = bp[col];
#pragma unroll
      for (int j = 0; j < 4; ++j) {
        const int row = m0 + wm * 128 + mi * 16 + (l >> 4) * 4 + j;
        float val = acc[mi][ni][j] + bv;
        if constexpr (EPI == 0) {
          const int b = row >> 11, t = row & 2047, hh = col >> 6, d = col & 63;
          if (seg == 0)
            ((bf16*)out)[(((size_t)(b * 16 + hh) * 2048 + t) * 64) + d] = (bf16)(val * 0.125f);
          else if (seg == 1)
            ((bf16*)outK)[(((size_t)(b * 16 + hh) * 2048 + t) * 64) + d] = (bf16)val;
          else
            ((bf16*)outV)[(((size_t)(b * 16 + hh) * 64 + d) * 2048) + t] = (bf16)val;
        } else if constexpr (EPI == 3) {
          ((float*)out)[(size_t)row * 1024 + col] = val + res[(size_t)row * 1024 + col];
        } else if constexpr (EPI == 4) {
          const float ge = 0.5f * val * (1.0f + erff(val * 0.70710678118f));
          ((bf16*)out)[(size_t)row * N + col] = (bf16)ge;
        } else if constexpr (EPI == 5) {
          ((float*)out)[(size_t)row * 1024 + col] = val + res[(size_t)row * 1024 + col];
        }
      }
    }
  }
}

// ======================= flash attention, swapped-QK^T + defer-max =======================
// q: [B,H,T,64] bf16 PRE-SCALED by 1/8; k: [B,H,T,64]; v: [B,H,64,T]; y: [B,T,1024] bf16
__global__ __launch_bounds__(512)
void attn_kernel(const bf16* __restrict__ q, const bf16* __restrict__ k,
                 const bf16* __restrict__ v, bf16* __restrict__ y,
                 const int* __restrict__ condp)
{
  __shared__ bf16 Ks[2][64 * 72];
  __shared__ bf16 Vs[2][64 * 72];
  __shared__ char PsB[8][2048];
  const int tid = threadIdx.x, l = tid & 63, w = tid >> 6;
  const int bx = blockIdx.x;
  const int qt = 15 - (bx >> 6);
  const int bh = bx & 63;
  const int bb = bh >> 4, hh = bh & 15;
  const int cond = condp[0];
  const int iLo = qt * 128;
  const size_t base = (size_t)bh * 2048 * 64;

  const int lrow = l & 15;
  const int g = l >> 4;
  const int lslot = g * 8;

  const int qrow = iLo + w * 16 + lrow;
  const bf16x8 bq0 = *(const bf16x8*)(q + base + (size_t)qrow * 64 + lslot);
  const bf16x8 bq1 = *(const bf16x8*)(q + base + (size_t)qrow * 64 + 32 + lslot);

  f32x4 o[4] = {};
  float m = -1e30f, lsum = 0.f;

  const int ckt = (cond + 63) >> 6;
  int nkt = ((iLo + 127) >> 6) + 1;
  if (nkt < ckt) nkt = ckt;
  const int wHi = iLo + w * 16 + 15;

  const int kr = tid >> 3;
  const int ks8 = (tid & 7) * 8;
  const bf16* kp = k + base + (size_t)kr * 64 + ks8;
  const bf16* vp = v + base + (size_t)kr * 2048 + ks8;

  bf16x8 rk = *(const bf16x8*)kp;
  bf16x8 rv = *(const bf16x8*)vp;
  *(bf16x8*)&Ks[0][kr * 72 + ks8] = rk;
  *(bf16x8*)&Vs[0][kr * 72 + ks8] = rv;
  __syncthreads();

  char* psw = PsB[w];

  for (int kt = 0; kt < nkt; ++kt) {
    const int cur = kt & 1;
    const int j0 = kt << 6;
    const bool pf = (kt + 1 < nkt);
    if (pf) {
      rk = *(const bf16x8*)(kp + (size_t)(j0 + 64) * 64);
      rv = *(const bf16x8*)(vp + j0 + 64);
    }

    const bool active = (j0 < cond) || (j0 <= wHi);
    if (active) {
      f32x4 sfr[4];
      __builtin_amdgcn_s_setprio(1);
#pragma unroll
      for (int nf = 0; nf < 4; ++nf) {
        f32x4 s = {};
        bf16x8 ka0 = *(const bf16x8*)&Ks[cur][(nf * 16 + lrow) * 72 + lslot];
        bf16x8 ka1 = *(const bf16x8*)&Ks[cur][(nf * 16 + lrow) * 72 + 32 + lslot];
        s = __builtin_amdgcn_mfma_f32_16x16x32_bf16(ka0, bq0, s, 0, 0, 0);
        s = __builtin_amdgcn_mfma_f32_16x16x32_bf16(ka1, bq1, s, 0, 0, 0);
        sfr[nf] = s;
      }
      __builtin_amdgcn_s_setprio(0);

      const bool safe = (j0 + 63 < cond) || (j0 + 63 <= iLo + w * 16);
      if (!safe) {
#pragma unroll
        for (int nf = 0; nf < 4; ++nf)
#pragma unroll
          for (int j = 0; j < 4; ++j) {
            const int kc = j0 + nf * 16 + g * 4 + j;
            const bool ok = (kc < cond) || (kc <= qrow);
            sfr[nf][j] = ok ? sfr[nf][j] : -1e30f;
          }
      }

      float pmax = sfr[0][0];
#pragma unroll
      for (int nf = 0; nf < 4; ++nf)
#pragma unroll
        for (int j = 0; j < 4; ++j) pmax = fmaxf(pmax, sfr[nf][j]);
      pmax = fmaxf(pmax, __shfl_xor(pmax, 16));
      pmax = fmaxf(pmax, __shfl_xor(pmax, 32));

      const bool resc = !__all(pmax - m <= 8.0f);
      if (resc) {
        const float mnew = fmaxf(m, pmax);
        const float alpha = __expf(m - mnew);
        m = mnew;
        lsum *= alpha;
        float ar[4];
#pragma unroll
        for (int j = 0; j < 4; ++j) ar[j] = __shfl(alpha, (l & 48) | (g * 4 + j));
#pragma unroll
        for (int df = 0; df < 4; ++df)
#pragma unroll
          for (int j = 0; j < 4; ++j) o[df][j] *= ar[j];
      }

      float rsum = 0.f;
#pragma unroll
      for (int nf = 0; nf < 4; ++nf) {
        bf16x4 pk;
#pragma unroll
        for (int j = 0; j < 4; ++j) {
          const float p = __expf(sfr[nf][j] - m);
          rsum += p;
          pk[j] = (bf16)p;
        }
        const int slot = 2 * nf + (g >> 1);
        const int boff = lrow * 128 + ((slot ^ (lrow & 7)) << 4) + (g & 1) * 8;
        *(bf16x4*)(psw + boff) = pk;
      }
      rsum += __shfl_xor(rsum, 16);
      rsum += __shfl_xor(rsum, 32);
      lsum += rsum;

      const int r0b = lrow * 128 + (((g) ^ (lrow & 7)) << 4);
      const int r1b = lrow * 128 + (((g + 4) ^ (lrow & 7)) << 4);
      const bf16x8 pa0 = *(const bf16x8*)(psw + r0b);
      const bf16x8 pa1 = *(const bf16x8*)(psw + r1b);
      __builtin_amdgcn_s_setprio(1);
#pragma unroll
      for (int df = 0; df < 4; ++df) {
        bf16x8 v0 = *(const bf16x8*)&Vs[cur][(df * 16 + lrow) * 72 + lslot];
        bf16x8 v1 = *(const bf16x8*)&Vs[cur][(df * 16 + lrow) * 72 + 32 + lslot];
        o[df] = __builtin_amdgcn_mfma_f32_16x16x32_bf16(pa0, v0, o[df], 0, 0, 0);
        o[df] = __builtin_amdgcn_mfma_f32_16x16x32_bf16(pa1, v1, o[df], 0, 0, 0);
      }
      __builtin_amdgcn_s_setprio(0);
    }

    if (pf) {
      *(bf16x8*)&Ks[cur ^ 1][kr * 72 + ks8] = rk;
      *(bf16x8*)&Vs[cur ^ 1][kr * 72 + ks8] = rv;
    }
    __syncthreads();
  }

  float lr[4];
#pragma unroll
  for (int j = 0; j < 4; ++j) lr[j] = 1.0f / __shfl(lsum, (l & 48) | (g * 4 + j));
#pragma unroll
  for (int df = 0; df < 4; ++df)
#pragma unroll
    for (int j = 0; j < 4; ++j) {
      const int irow = iLo + w * 16 + g * 4 + j;
      y[((size_t)bb * 2048 + irow) * 1024 + hh * 64 + df * 16 + lrow] = (bf16)(o[df][j] * lr[j]);
    }
}

// ======================= launcher =======================
extern "C" void kernel_launch(void* const* d_in, const int* in_sizes, int n_in,
                              void* d_out, int out_size, void* d_ws, size_t ws_size,
                              hipStream_t stream) {
  const float* x    = (const float*)d_in[0];
  const float* ln1g = (const float*)d_in[1];
  const float* ln1b = (const float*)d_in[2];
  const float* Wk   = (const float*)d_in[3];
  const float* bk   = (const float*)d_in[4];
  const float* Wq   = (const float*)d_in[5];
  const float* bq   = (const float*)d_in[6];
  const float* Wv   = (const float*)d_in[7];
  const float* bv   = (const float*)d_in[8];
  const float* Wp   = (const float*)d_in[9];
  const float* bpb  = (const float*)d_in[10];
  const float* ln2g = (const float*)d_in[11];
  const float* ln2b = (const float*)d_in[12];
  const float* W1   = (const float*)d_in[13];
  const float* b1   = (const float*)d_in[14];
  const float* W2   = (const float*)d_in[15];
  const float* b2   = (const float*)d_in[16];
  const int*  cond  = (const int*)d_in[17];
  float* out = (float*)d_out;

  char* ws = (char*)d_ws;
  const size_t MB = 1024ull * 1024ull;
  if (ws_size < 136 * MB) return;

  bf16*  WqkvT = (bf16*)(ws + 0 * MB);   // [3072][1024] bf16 = 6 MB (Q,K,V stacked)
  bf16*  WpT   = (bf16*)(ws + 6 * MB);
  bf16*  W1T   = (bf16*)(ws + 8 * MB);
  bf16*  W2T   = (bf16*)(ws + 16 * MB);
  float* x2    = (float*)(ws + 24 * MB);
  bf16*  hbuf  = (bf16*)(ws + 56 * MB);
  bf16*  qb    = (bf16*)(ws + 72 * MB);
  bf16*  kb    = (bf16*)(ws + 88 * MB);
  bf16*  vb    = (bf16*)(ws + 104 * MB);
  bf16*  yb    = (bf16*)(ws + 120 * MB);
  bf16*  m1    = (bf16*)(ws + 72 * MB);  // 64 MB, reuses qb..yb (dead by FC1)

  dim3 blk(256);
  transpose_f32_bf16<<<dim3(32, 32), blk, 0, stream>>>(Wq, WqkvT,                1024, 1024);
  transpose_f32_bf16<<<dim3(32, 32), blk, 0, stream>>>(Wk, WqkvT + 1024 * 1024,  1024, 1024);
  transpose_f32_bf16<<<dim3(32, 32), blk, 0, stream>>>(Wv, WqkvT + 2048 * 1024,  1024, 1024);
  transpose_f32_bf16<<<dim3(32, 32), blk, 0, stream>>>(Wp, WpT, 1024, 1024);
  transpose_f32_bf16<<<dim3(128, 32), blk, 0, stream>>>(W1, W1T, 1024, 4096);
  transpose_f32_bf16<<<dim3(32, 128), blk, 0, stream>>>(W2, W2T, 4096, 1024);

  ln_f32_bf16<<<2048, blk, 0, stream>>>(x, ln1g, ln1b, hbuf);

  gemm_bt<0><<<dim3(32, 12), dim3(512), 0, stream>>>(hbuf, WqkvT, bq, bk, bv,
                                                     qb, kb, vb, nullptr, 8192, 3072, 1024);

  attn_kernel<<<dim3(1024), dim3(512), 0, stream>>>(qb, kb, vb, yb, cond);

  gemm_bt<3><<<dim3(32, 4), dim3(512), 0, stream>>>(yb, WpT, bpb, nullptr, nullptr,
                                                    x2, nullptr, nullptr, x, 8192, 1024, 1024);
  ln_f32_bf16<<<2048, blk, 0, stream>>>(x2, ln2g, ln2b, hbuf);
  gemm_bt<4><<<dim3(32, 16), dim3(512), 0, stream>>>(hbuf, W1T, b1, nullptr, nullptr,
                                                     m1, nullptr, nullptr, nullptr, 8192, 4096, 1024);
  gemm_bt<5><<<dim3(32, 4), dim3(512), 0, stream>>>(m1, W2T, b2, nullptr, nullptr,
                                                    out, nullptr, nullptr, x2, 8192, 1024, 4096);
}

// Round 8
// 409.508 us; speedup vs baseline: 1.1516x; 1.1516x over previous
//
#include <hip/hip_runtime.h>

typedef __bf16 bf16;
typedef __attribute__((ext_vector_type(4))) __bf16 bf16x4;
typedef __attribute__((ext_vector_type(8))) __bf16 bf16x8;
typedef __attribute__((ext_vector_type(4))) float f32x4;

__device__ __forceinline__ void stage16(const bf16* g, bf16* l) {
  __builtin_amdgcn_global_load_lds(
      (const __attribute__((address_space(1))) void*)g,
      (__attribute__((address_space(3))) void*)l, 16, 0, 0);
}

// ============= convert+transpose (fp32 [R][C] -> bf16 [C][R]) =============
__global__ __launch_bounds__(256)
void transpose_f32_bf16(const float* __restrict__ src, bf16* __restrict__ dst, int R, int C)
{
  __shared__ bf16 tile[32][33];
  const int tx = threadIdx.x & 31, ty = threadIdx.x >> 5;
  const int c0 = blockIdx.x * 32, r0 = blockIdx.y * 32;
#pragma unroll
  for (int i = 0; i < 4; ++i)
    tile[ty + i * 8][tx] = (bf16)src[(size_t)(r0 + ty + i * 8) * C + c0 + tx];
  __syncthreads();
#pragma unroll
  for (int i = 0; i < 4; ++i)
    dst[(size_t)(c0 + ty + i * 8) * R + r0 + tx] = tile[tx][ty + i * 8];
}

// ============= layernorm: fp32 in -> bf16 out (one wave per 1024-col row) =============
__global__ __launch_bounds__(256)
void ln_f32_bf16(const float* __restrict__ x, const float* __restrict__ g,
                 const float* __restrict__ bta, bf16* __restrict__ out)
{
  const int row = blockIdx.x * 4 + (threadIdx.x >> 6);
  const int l = threadIdx.x & 63;
  const float* xr = x + (size_t)row * 1024 + l * 16;
  f32x4 a[4];
#pragma unroll
  for (int i = 0; i < 4; ++i) a[i] = ((const f32x4*)xr)[i];
  float s = 0.f, s2 = 0.f;
#pragma unroll
  for (int i = 0; i < 4; ++i)
#pragma unroll
    for (int jj = 0; jj < 4; ++jj) { float vv = a[i][jj]; s += vv; s2 += vv * vv; }
#pragma unroll
  for (int m = 1; m < 64; m <<= 1) { s += __shfl_xor(s, m); s2 += __shfl_xor(s2, m); }
  const float mu = s * (1.0f / 1024.0f);
  const float var = s2 * (1.0f / 1024.0f) - mu * mu;
  const float rs = rsqrtf(var + 1e-5f);
  f32x4 gv[4], bv[4];
#pragma unroll
  for (int i = 0; i < 4; ++i) {
    gv[i] = ((const f32x4*)(g + l * 16))[i];
    bv[i] = ((const f32x4*)(bta + l * 16))[i];
  }
  bf16x8 o0, o1;
#pragma unroll
  for (int i = 0; i < 8; ++i) {
    float v0 = a[i >> 2][i & 3];
    float v1 = a[2 + (i >> 2)][i & 3];
    o0[i] = (bf16)((v0 - mu) * rs * gv[i >> 2][i & 3] + bv[i >> 2][i & 3]);
    o1[i] = (bf16)((v1 - mu) * rs * gv[2 + (i >> 2)][i & 3] + bv[2 + (i >> 2)][i & 3]);
  }
  bf16* orow = out + (size_t)row * 1024 + l * 16;
  ((bf16x8*)orow)[0] = o0;
  ((bf16x8*)orow)[1] = o1;
}

// ======== GEMM: C[M,N] = A[M,K] @ Bt[N,K]^T, gll 3-buf depth-2 + counted vmcnt ========
// LDS linear [128][32] per buffer (global_load_lds contract); source pre-swizzled
// with slot ^= (row>>1)&3 so swizzled reads are bank-conflict-free (rule #21).
// EPI: 0 = fused QKV (seg 0: q*0.125 [B,H,T,hd]; seg 1: k [B,H,T,hd]; seg 2: v [B,H,hd,T])
//      3 = fp32 out = acc + bias + fp32 residual (proj);
//      4 = bf16 out = gelu(acc + bias)  [tanh form];
//      5 = fp32 out = acc + bias + fp32 residual (final).
template <int EPI>
__global__ __launch_bounds__(256)
void gemm_bt(const bf16* __restrict__ A, const bf16* __restrict__ Bt,
             const float* __restrict__ bias, const float* __restrict__ biasK,
             const float* __restrict__ biasV,
             void* __restrict__ out, void* __restrict__ outK, void* __restrict__ outV,
             const float* __restrict__ res, int M, int N, int K)
{
  __shared__ bf16 As[3][128 * 32];   // 24 KB
  __shared__ bf16 Bs[3][128 * 32];   // 24 KB
  const int tid = threadIdx.x;
  const int l = tid & 63;
  const int w = tid >> 6;
  const int wm = w >> 1, wn = w & 1;
  const int m0 = blockIdx.x * 128;   // natural order: consecutive blocks share n0
  const int n0 = blockIdx.y * 128;

  // staging: thread t -> LDS row t>>2, 16B slot t&3 (linear); global col pre-swizzled
  const int srow = tid >> 2;
  const int sG8 = ((tid & 3) ^ ((tid >> 3) & 3)) * 8;
  const bf16* gA = A + (size_t)(m0 + srow) * K + sG8;
  const bf16* gB = Bt + (size_t)(n0 + srow) * K + sG8;
  const int ldsOff = srow * 32 + (tid & 3) * 8;

  const int lrow = l & 15;
  const int rdsl = ((l >> 4) ^ ((lrow >> 1) & 3)) * 8;  // swizzled read slot (elems)

  f32x4 acc[4][4] = {};
  const int KT = K >> 5;

#define STAGE(buf, k0)                                            \
  do {                                                            \
    stage16(gA + (k0), &As[buf][ldsOff]);                         \
    stage16(gA + (size_t)64 * K + (k0), &As[buf][2048 + ldsOff]); \
    stage16(gB + (k0), &Bs[buf][ldsOff]);                         \
    stage16(gB + (size_t)64 * K + (k0), &Bs[buf][2048 + ldsOff]); \
  } while (0)

  STAGE(0, 0);
  if (KT > 1) STAGE(1, 32);

  int cur = 0;
  for (int kt = 0; kt < KT; ++kt) {
    const int stg = (cur == 0) ? 2 : cur - 1;   // (cur+2)%3
    __builtin_amdgcn_s_barrier();               // B1: buf stg's readers (iter kt-1) done
    if (kt + 2 < KT) {
      STAGE(stg, (kt + 2) << 5);                // depth-2: tile t+2 in flight
      asm volatile("s_waitcnt vmcnt(8)" ::: "memory");   // tile t's 4 loads complete
    } else if (kt + 1 < KT) {
      asm volatile("s_waitcnt vmcnt(4)" ::: "memory");
    } else {
      asm volatile("s_waitcnt vmcnt(0)" ::: "memory");
    }
    __builtin_amdgcn_sched_barrier(0);
    __builtin_amdgcn_s_barrier();               // B2: everyone's tile-t loads complete

    bf16x8 af[4], bfv[4];
#pragma unroll
    for (int i = 0; i < 4; ++i)
      af[i] = *(const bf16x8*)&As[cur][(wm * 64 + i * 16 + lrow) * 32 + rdsl];
#pragma unroll
    for (int i = 0; i < 4; ++i)
      bfv[i] = *(const bf16x8*)&Bs[cur][(wn * 64 + i * 16 + lrow) * 32 + rdsl];
#pragma unroll
    for (int mi = 0; mi < 4; ++mi)
#pragma unroll
      for (int ni = 0; ni < 4; ++ni)
        acc[mi][ni] = __builtin_amdgcn_mfma_f32_16x16x32_bf16(af[mi], bfv[ni], acc[mi][ni], 0, 0, 0);
    cur = (cur == 2) ? 0 : cur + 1;
  }
#undef STAGE

  // epilogue: C/D layout col = lane&15, row = (lane>>4)*4 + j
  const int seg = n0 >> 10;   // block-uniform (EPI 0 only)
  const float* bp = (EPI == 0) ? (seg == 0 ? bias : (seg == 1 ? biasK : biasV)) : bias;
#pragma unroll
  for (int mi = 0; mi < 4; ++mi) {
#pragma unroll
    for (int ni = 0; ni < 4; ++ni) {
      const int colg = n0 + wn * 64 + ni * 16 + lrow;
      const int col = (EPI == 0) ? (colg & 1023) : colg;
      const float bv = bp[col];
#pragma unroll
      for (int j = 0; j < 4; ++j) {
        const int row = m0 + wm * 64 + mi * 16 + (l >> 4) * 4 + j;
        float val = acc[mi][ni][j] + bv;
        if constexpr (EPI == 0) {
          const int b = row >> 11, t = row & 2047, hh = col >> 6, d = col & 63;
          if (seg == 0)
            ((bf16*)out)[(((size_t)(b * 16 + hh) * 2048 + t) * 64) + d] = (bf16)(val * 0.125f);
          else if (seg == 1)
            ((bf16*)outK)[(((size_t)(b * 16 + hh) * 2048 + t) * 64) + d] = (bf16)val;
          else
            ((bf16*)outV)[(((size_t)(b * 16 + hh) * 64 + d) * 2048) + t] = (bf16)val;
        } else if constexpr (EPI == 3) {
          ((float*)out)[(size_t)row * 1024 + col] = val + res[(size_t)row * 1024 + col];
        } else if constexpr (EPI == 4) {
          // tanh-form GELU (|err| < 3e-3 vs exact erf form; threshold 0.115)
          const float u = 0.7978845608f * (val + 0.044715f * val * val * val);
          const float e = __expf(2.0f * u);
          const float th = 1.0f - 2.0f / (e + 1.0f);
          const float ge = 0.5f * val * (1.0f + th);
          ((bf16*)out)[(size_t)row * N + col] = (bf16)ge;
        } else if constexpr (EPI == 5) {
          ((float*)out)[(size_t)row * 1024 + col] = val + res[(size_t)row * 1024 + col];
        }
      }
    }
  }
}

// ======================= flash attention, swapped-QK^T + defer-max =======================
// q: [B,H,T,64] bf16 PRE-SCALED by 1/8; k: [B,H,T,64]; v: [B,H,64,T]; y: [B,T,1024] bf16
__global__ __launch_bounds__(512)
void attn_kernel(const bf16* __restrict__ q, const bf16* __restrict__ k,
                 const bf16* __restrict__ v, bf16* __restrict__ y,
                 const int* __restrict__ condp)
{
  __shared__ bf16 Ks[2][64 * 72];
  __shared__ bf16 Vs[2][64 * 72];
  __shared__ char PsB[8][2048];
  const int tid = threadIdx.x, l = tid & 63, w = tid >> 6;
  const int bx = blockIdx.x;
  const int qt = 15 - (bx >> 6);
  const int bh = bx & 63;
  const int bb = bh >> 4, hh = bh & 15;
  const int cond = condp[0];
  const int iLo = qt * 128;
  const size_t base = (size_t)bh * 2048 * 64;

  const int lrow = l & 15;
  const int g = l >> 4;
  const int lslot = g * 8;

  const int qrow = iLo + w * 16 + lrow;
  const bf16x8 bq0 = *(const bf16x8*)(q + base + (size_t)qrow * 64 + lslot);
  const bf16x8 bq1 = *(const bf16x8*)(q + base + (size_t)qrow * 64 + 32 + lslot);

  f32x4 o[4] = {};
  float m = -1e30f, lsum = 0.f;

  const int ckt = (cond + 63) >> 6;
  int nkt = ((iLo + 127) >> 6) + 1;
  if (nkt < ckt) nkt = ckt;
  const int wHi = iLo + w * 16 + 15;

  const int kr = tid >> 3;
  const int ks8 = (tid & 7) * 8;
  const bf16* kp = k + base + (size_t)kr * 64 + ks8;
  const bf16* vp = v + base + (size_t)kr * 2048 + ks8;

  bf16x8 rk = *(const bf16x8*)kp;
  bf16x8 rv = *(const bf16x8*)vp;
  *(bf16x8*)&Ks[0][kr * 72 + ks8] = rk;
  *(bf16x8*)&Vs[0][kr * 72 + ks8] = rv;
  __syncthreads();

  char* psw = PsB[w];

  for (int kt = 0; kt < nkt; ++kt) {
    const int cur = kt & 1;
    const int j0 = kt << 6;
    const bool pf = (kt + 1 < nkt);
    if (pf) {
      rk = *(const bf16x8*)(kp + (size_t)(j0 + 64) * 64);
      rv = *(const bf16x8*)(vp + j0 + 64);
    }

    const bool active = (j0 < cond) || (j0 <= wHi);
    if (active) {
      f32x4 sfr[4];
      __builtin_amdgcn_s_setprio(1);
#pragma unroll
      for (int nf = 0; nf < 4; ++nf) {
        f32x4 s = {};
        bf16x8 ka0 = *(const bf16x8*)&Ks[cur][(nf * 16 + lrow) * 72 + lslot];
        bf16x8 ka1 = *(const bf16x8*)&Ks[cur][(nf * 16 + lrow) * 72 + 32 + lslot];
        s = __builtin_amdgcn_mfma_f32_16x16x32_bf16(ka0, bq0, s, 0, 0, 0);
        s = __builtin_amdgcn_mfma_f32_16x16x32_bf16(ka1, bq1, s, 0, 0, 0);
        sfr[nf] = s;
      }
      __builtin_amdgcn_s_setprio(0);

      const bool safe = (j0 + 63 < cond) || (j0 + 63 <= iLo + w * 16);
      if (!safe) {
#pragma unroll
        for (int nf = 0; nf < 4; ++nf)
#pragma unroll
          for (int j = 0; j < 4; ++j) {
            const int kc = j0 + nf * 16 + g * 4 + j;
            const bool ok = (kc < cond) || (kc <= qrow);
            sfr[nf][j] = ok ? sfr[nf][j] : -1e30f;
          }
      }

      float pmax = sfr[0][0];
#pragma unroll
      for (int nf = 0; nf < 4; ++nf)
#pragma unroll
        for (int j = 0; j < 4; ++j) pmax = fmaxf(pmax, sfr[nf][j]);
      pmax = fmaxf(pmax, __shfl_xor(pmax, 16));
      pmax = fmaxf(pmax, __shfl_xor(pmax, 32));

      const bool resc = !__all(pmax - m <= 8.0f);
      if (resc) {
        const float mnew = fmaxf(m, pmax);
        const float alpha = __expf(m - mnew);
        m = mnew;
        lsum *= alpha;
        float ar[4];
#pragma unroll
        for (int j = 0; j < 4; ++j) ar[j] = __shfl(alpha, (l & 48) | (g * 4 + j));
#pragma unroll
        for (int df = 0; df < 4; ++df)
#pragma unroll
          for (int j = 0; j < 4; ++j) o[df][j] *= ar[j];
      }

      float rsum = 0.f;
#pragma unroll
      for (int nf = 0; nf < 4; ++nf) {
        bf16x4 pk;
#pragma unroll
        for (int j = 0; j < 4; ++j) {
          const float p = __expf(sfr[nf][j] - m);
          rsum += p;
          pk[j] = (bf16)p;
        }
        const int slot = 2 * nf + (g >> 1);
        const int boff = lrow * 128 + ((slot ^ (lrow & 7)) << 4) + (g & 1) * 8;
        *(bf16x4*)(psw + boff) = pk;
      }
      rsum += __shfl_xor(rsum, 16);
      rsum += __shfl_xor(rsum, 32);
      lsum += rsum;

      const int r0b = lrow * 128 + (((g) ^ (lrow & 7)) << 4);
      const int r1b = lrow * 128 + (((g + 4) ^ (lrow & 7)) << 4);
      const bf16x8 pa0 = *(const bf16x8*)(psw + r0b);
      const bf16x8 pa1 = *(const bf16x8*)(psw + r1b);
      __builtin_amdgcn_s_setprio(1);
#pragma unroll
      for (int df = 0; df < 4; ++df) {
        bf16x8 v0 = *(const bf16x8*)&Vs[cur][(df * 16 + lrow) * 72 + lslot];
        bf16x8 v1 = *(const bf16x8*)&Vs[cur][(df * 16 + lrow) * 72 + 32 + lslot];
        o[df] = __builtin_amdgcn_mfma_f32_16x16x32_bf16(pa0, v0, o[df], 0, 0, 0);
        o[df] = __builtin_amdgcn_mfma_f32_16x16x32_bf16(pa1, v1, o[df], 0, 0, 0);
      }
      __builtin_amdgcn_s_setprio(0);
    }

    if (pf) {
      *(bf16x8*)&Ks[cur ^ 1][kr * 72 + ks8] = rk;
      *(bf16x8*)&Vs[cur ^ 1][kr * 72 + ks8] = rv;
    }
    __syncthreads();
  }

  float lr[4];
#pragma unroll
  for (int j = 0; j < 4; ++j) lr[j] = 1.0f / __shfl(lsum, (l & 48) | (g * 4 + j));
#pragma unroll
  for (int df = 0; df < 4; ++df)
#pragma unroll
    for (int j = 0; j < 4; ++j) {
      const int irow = iLo + w * 16 + g * 4 + j;
      y[((size_t)bb * 2048 + irow) * 1024 + hh * 64 + df * 16 + lrow] = (bf16)(o[df][j] * lr[j]);
    }
}

// ======================= launcher =======================
extern "C" void kernel_launch(void* const* d_in, const int* in_sizes, int n_in,
                              void* d_out, int out_size, void* d_ws, size_t ws_size,
                              hipStream_t stream) {
  const float* x    = (const float*)d_in[0];
  const float* ln1g = (const float*)d_in[1];
  const float* ln1b = (const float*)d_in[2];
  const float* Wk   = (const float*)d_in[3];
  const float* bk   = (const float*)d_in[4];
  const float* Wq   = (const float*)d_in[5];
  const float* bq   = (const float*)d_in[6];
  const float* Wv   = (const float*)d_in[7];
  const float* bv   = (const float*)d_in[8];
  const float* Wp   = (const float*)d_in[9];
  const float* bpb  = (const float*)d_in[10];
  const float* ln2g = (const float*)d_in[11];
  const float* ln2b = (const float*)d_in[12];
  const float* W1   = (const float*)d_in[13];
  const float* b1   = (const float*)d_in[14];
  const float* W2   = (const float*)d_in[15];
  const float* b2   = (const float*)d_in[16];
  const int*  cond  = (const int*)d_in[17];
  float* out = (float*)d_out;

  char* ws = (char*)d_ws;
  const size_t MB = 1024ull * 1024ull;
  if (ws_size < 136 * MB) return;

  bf16*  WqkvT = (bf16*)(ws + 0 * MB);   // [3072][1024] bf16 = 6 MB (Q,K,V stacked)
  bf16*  WpT   = (bf16*)(ws + 6 * MB);
  bf16*  W1T   = (bf16*)(ws + 8 * MB);
  bf16*  W2T   = (bf16*)(ws + 16 * MB);
  float* x2    = (float*)(ws + 24 * MB);
  bf16*  hbuf  = (bf16*)(ws + 56 * MB);
  bf16*  qb    = (bf16*)(ws + 72 * MB);
  bf16*  kb    = (bf16*)(ws + 88 * MB);
  bf16*  vb    = (bf16*)(ws + 104 * MB);
  bf16*  yb    = (bf16*)(ws + 120 * MB);
  bf16*  m1    = (bf16*)(ws + 72 * MB);  // 64 MB, reuses qb..yb (dead by FC1)

  dim3 blk(256);
  transpose_f32_bf16<<<dim3(32, 32), blk, 0, stream>>>(Wq, WqkvT,                1024, 1024);
  transpose_f32_bf16<<<dim3(32, 32), blk, 0, stream>>>(Wk, WqkvT + 1024 * 1024,  1024, 1024);
  transpose_f32_bf16<<<dim3(32, 32), blk, 0, stream>>>(Wv, WqkvT + 2048 * 1024,  1024, 1024);
  transpose_f32_bf16<<<dim3(32, 32), blk, 0, stream>>>(Wp, WpT, 1024, 1024);
  transpose_f32_bf16<<<dim3(128, 32), blk, 0, stream>>>(W1, W1T, 1024, 4096);
  transpose_f32_bf16<<<dim3(32, 128), blk, 0, stream>>>(W2, W2T, 4096, 1024);

  ln_f32_bf16<<<2048, blk, 0, stream>>>(x, ln1g, ln1b, hbuf);

  gemm_bt<0><<<dim3(64, 24), blk, 0, stream>>>(hbuf, WqkvT, bq, bk, bv,
                                               qb, kb, vb, nullptr, 8192, 3072, 1024);

  attn_kernel<<<dim3(1024), dim3(512), 0, stream>>>(qb, kb, vb, yb, cond);

  gemm_bt<3><<<dim3(64, 8), blk, 0, stream>>>(yb, WpT, bpb, nullptr, nullptr,
                                              x2, nullptr, nullptr, x, 8192, 1024, 1024);
  ln_f32_bf16<<<2048, blk, 0, stream>>>(x2, ln2g, ln2b, hbuf);
  gemm_bt<4><<<dim3(64, 32), blk, 0, stream>>>(hbuf, W1T, b1, nullptr, nullptr,
                                               m1, nullptr, nullptr, nullptr, 8192, 4096, 1024);
  gemm_bt<5><<<dim3(64, 8), blk, 0, stream>>>(m1, W2T, b2, nullptr, nullptr,
                                              out, nullptr, nullptr, x2, 8192, 1024, 4096);
}